// Round 10
// baseline (212.983 us; speedup 1.0000x reference)
//
#include <hip/hip_runtime.h>
#include <hip/hip_bf16.h>

// GCN: out = (segment_sum over edges+selfloops of norm * emb[src]) @ W, gathered at `nodes`.
// Round 10: k_gemm_h re-tiled as full-K / 32-row blocks: ONE 64 KB bulk DMA per block
// (contiguous 2 KB per row -> ideal DRAM), single vmcnt(0)+barrier, then 16 MFMA K-steps
// from LDS with B (128 KB wt, L2-hot) read straight to registers. Rounds 8-9's K-chunked
// double/triple-buffer pipelines were structurally latency-fragile (128B strided reads,
// depth-2 exactly borderline) and plateaued at ~85 us vs ~37 us HBM floor.

constexpr int KDIM = 512;   // embedding dim
constexpr int CDIM = 128;   // output channels
constexpr int CAPB = 64;    // bucket capacity per slot (Poisson(16); P(X>=64)~1e-19)
constexpr int CAPO = 16;    // max duplicate output rows per node

typedef __attribute__((ext_vector_type(8))) short short8;   // 8 bf16 (A/B frag)
typedef __attribute__((ext_vector_type(4))) float f32x4;    // C/D frag

static __device__ __forceinline__ unsigned short f2bf(float f) {
    unsigned u = __float_as_uint(f);
    unsigned r = ((u >> 16) & 1u) + 0x7fffu;     // round-to-nearest-even
    return (unsigned short)((u + r) >> 16);
}
static __device__ __forceinline__ float bf2f(unsigned short b) {
    return __uint_as_float(((unsigned)b) << 16);
}

// ---- fused initialization: deg=0, tmap=-1, cur=0, ocnt=0, ucount=0 ----
__global__ void k_init(int* __restrict__ deg, int* __restrict__ tmap,
                       int* __restrict__ cur, int* __restrict__ ocnt,
                       int* __restrict__ ucount, int N, int n) {
    int i = blockIdx.x * blockDim.x + threadIdx.x;
    if (i < N) { deg[i] = 0; tmap[i] = -1; }
    if (i < n) { cur[i] = 0; ocnt[i] = 0; }
    if (i == 0) *ucount = 0;
}

// ---- unique-target compaction: tmap[node] = slot or -1 ----
__global__ void k_targets(const int* __restrict__ nodes, int n,
                          int* __restrict__ tmap, int* __restrict__ tlist,
                          int* __restrict__ ucount) {
    int i = blockIdx.x * blockDim.x + threadIdx.x;
    if (i >= n) return;
    int v = nodes[i];
    if (atomicCAS(&tmap[v], -1, -2) == -1) {   // claim
        int slot = atomicAdd(ucount, 1);
        tlist[slot] = v;
        tmap[v] = slot;                        // only the claimer writes
    }
}

// ---- slot -> list of output rows (handles duplicate nodes) ----
__global__ void k_outmap(const int* __restrict__ nodes, int n,
                         const int* __restrict__ tmap,
                         int* __restrict__ ocnt, int* __restrict__ olist) {
    int i = blockIdx.x * blockDim.x + threadIdx.x;
    if (i >= n) return;
    int slot = tmap[nodes[i]];                 // always >= 0 after k_targets
    int p = atomicAdd(&ocnt[slot], 1);
    if (p < CAPO) olist[slot * CAPO + p] = i;
}

// ---- single edge pass: deg atomics + capacity-bucket fill ----
__global__ __launch_bounds__(256)
void k_degfill(const int* __restrict__ erow, const int* __restrict__ ecol, int E,
               int* __restrict__ deg, const int* __restrict__ tmap,
               int* __restrict__ cur, int* __restrict__ ebuf) {
    int t = blockIdx.x * blockDim.x + threadIdx.x;
    int base = t * 4;
    if (base >= E) return;
    if (base + 4 <= E) {
        int4 c = *reinterpret_cast<const int4*>(ecol + base);
        atomicAdd(&deg[c.x], 1);
        atomicAdd(&deg[c.y], 1);
        atomicAdd(&deg[c.z], 1);
        atomicAdd(&deg[c.w], 1);
        int s0 = tmap[c.x], s1 = tmap[c.y], s2 = tmap[c.z], s3 = tmap[c.w];
        if ((s0 >= 0) | (s1 >= 0) | (s2 >= 0) | (s3 >= 0)) {
            int4 r = *reinterpret_cast<const int4*>(erow + base);
            if (s0 >= 0) { int p = atomicAdd(&cur[s0], 1); if (p < CAPB) ebuf[s0 * CAPB + p] = r.x; }
            if (s1 >= 0) { int p = atomicAdd(&cur[s1], 1); if (p < CAPB) ebuf[s1 * CAPB + p] = r.y; }
            if (s2 >= 0) { int p = atomicAdd(&cur[s2], 1); if (p < CAPB) ebuf[s2 * CAPB + p] = r.z; }
            if (s3 >= 0) { int p = atomicAdd(&cur[s3], 1); if (p < CAPB) ebuf[s3 * CAPB + p] = r.w; }
        }
    } else {
        for (int i = base; i < E; ++i) {
            int c = ecol[i];
            atomicAdd(&deg[c], 1);
            int s = tmap[c];
            if (s >= 0) { int p = atomicAdd(&cur[s], 1); if (p < CAPB) ebuf[s * CAPB + p] = erow[i]; }
        }
    }
}

// ---- pack W (512x128 f32) into bf16 MFMA B-fragment layout ----
// frag (s,t): lane l holds B[k][c], k = s*32 + (l>>4)*8 + j, c = t*16 + (l&15).
// Linear: wt[((s*8+t)*64 + l)*8 + j].
__global__ void k_wprep(const float* __restrict__ W, unsigned short* __restrict__ wt) {
    int idx = blockIdx.x * 256 + threadIdx.x;   // 0..65535
    int j  = idx & 7;
    int l  = (idx >> 3) & 63;
    int st = idx >> 9;
    int t  = st & 7, s = st >> 3;
    int k  = s * 32 + (l >> 4) * 8 + j;
    int c  = t * 16 + (l & 15);
    wt[idx] = f2bf(W[(size_t)k * CDIM + c]);
}

// ---- dense h = emb @ W: full-K 32-row tile, one bulk DMA per block ----
// 256 thr / 4 waves (wr = wave>>1 row-group of 16, wc = wave&1 col-group of 64).
// A = 32 rows x 512 f32 = 64 KB LDS, staged by 16 global_load_lds(16B)/thread,
// each row = contiguous 2 KB global read. XOR swizzle chunk^(row&7) via
// pre-swizzled SOURCE (LDS dest linear; read applies same XOR) -> 2-way max.
// B frags read per K-step from wt (128 KB, L2-hot across all 3125 blocks).
__global__ __launch_bounds__(256, 2)
void k_gemm_h(const float* __restrict__ emb, const unsigned short* __restrict__ wt,
              unsigned short* __restrict__ h, int N) {
    extern __shared__ float sA[];            // 32 x 512 f32 = 64 KB
    int tid  = threadIdx.x;
    int wave = tid >> 6, lane = tid & 63;
    int row0 = blockIdx.x * 32;

    // ---- stage: 4096 x 16B chunks, rows contiguous ----
    #pragma unroll
    for (int p = 0; p < 16; ++p) {
        int i = p * 256 + tid;               // 0..4095
        int row   = i >> 7;                  // 128 chunks per row
        int chunk = i & 127;
        int swz   = chunk ^ (row & 7);       // source pre-swizzle (rule #21)
        int rg = row0 + row; if (rg >= N) rg = N - 1;
        const float* g = emb + (size_t)rg * KDIM + swz * 4;
        float* l = sA + (size_t)i * 4;
        __builtin_amdgcn_global_load_lds(
            (const __attribute__((address_space(1))) void*)g,
            (__attribute__((address_space(3))) void*)l, 16, 0, 0);
    }
    asm volatile("s_waitcnt vmcnt(0)" ::: "memory");
    __builtin_amdgcn_s_barrier();

    // ---- compute: 16 K-steps, B straight from L2 ----
    int wr = wave >> 1, wc = wave & 1;
    int arow = wr * 16 + (lane & 15);
    int kq   = lane >> 4;                    // k-quarter 0..3
    const float* Arow = sA + (size_t)arow * 512;
    f32x4 acc[4];
    #pragma unroll
    for (int t = 0; t < 4; ++t) acc[t] = (f32x4){0.f, 0.f, 0.f, 0.f};

    #pragma unroll 4
    for (int ks = 0; ks < 16; ++ks) {
        int c0 = ks * 8 + kq * 2;            // linear 16B-chunk of k = ks*32+kq*8
        int x  = c0 ^ (arow & 7);
        int y  = (c0 + 1) ^ (arow & 7);
        float4 v0 = *reinterpret_cast<const float4*>(Arow + x * 4);  // k+0..3
        float4 v1 = *reinterpret_cast<const float4*>(Arow + y * 4);  // k+4..7
        short8 af;
        af[0] = (short)f2bf(v0.x); af[1] = (short)f2bf(v0.y);
        af[2] = (short)f2bf(v0.z); af[3] = (short)f2bf(v0.w);
        af[4] = (short)f2bf(v1.x); af[5] = (short)f2bf(v1.y);
        af[6] = (short)f2bf(v1.z); af[7] = (short)f2bf(v1.w);
        const short8* wp = reinterpret_cast<const short8*>(wt)
                         + ((size_t)(ks * 8 + wc * 4)) * 64 + lane;
        #pragma unroll
        for (int tt = 0; tt < 4; ++tt) {
            short8 bf = wp[tt * 64];
            acc[tt] = __builtin_amdgcn_mfma_f32_16x16x32_bf16(af, bf, acc[tt], 0, 0, 0);
        }
    }

    // D layout (m89-verified): col = lane&15, row = (lane>>4)*4 + reg_idx
    int rbase = row0 + wr * 16 + (lane >> 4) * 4;
    int cbase = wc * 64 + (lane & 15);
    #pragma unroll
    for (int tt = 0; tt < 4; ++tt)
        #pragma unroll
        for (int j = 0; j < 4; ++j) {
            int r = rbase + j;
            if (r < N) h[(size_t)r * CDIM + cbase + tt * 16] = f2bf(acc[tt][j]);
        }
}

// ---- per-target aggregation over h (128-dim bf16): one wave per slot ----
__global__ __launch_bounds__(256)
void k_agg(const unsigned short* __restrict__ h, const int* __restrict__ deg,
           const int* __restrict__ tlist, const int* __restrict__ cur,
           const int* __restrict__ ebuf, const int* __restrict__ ucount,
           const int* __restrict__ ocnt, const int* __restrict__ olist,
           float* __restrict__ out) {
    int u = *ucount;
    int slot = blockIdx.x * 4 + (threadIdx.x >> 6);
    if (slot >= u) return;                 // wave-uniform exit
    int lane = threadIdx.x & 63;
    int e = min(cur[slot], CAPB);
    int myi = 0; float myw = 0.f;
    if (lane < e) {
        myi = ebuf[(size_t)slot * CAPB + lane];          // coalesced
        myw = rsqrtf((float)(deg[myi] + 1));
    }
    float ax = 0.f, ay = 0.f;
    #pragma unroll 4
    for (int j = 0; j < e; ++j) {
        int   src = __shfl(myi, j, 64);
        float w   = __shfl(myw, j, 64);
        unsigned v = *reinterpret_cast<const unsigned*>(h + (size_t)src * CDIM + lane * 2);
        ax += w * bf2f((unsigned short)(v & 0xffffu));
        ay += w * bf2f((unsigned short)(v >> 16));
    }
    int t = tlist[slot];
    float dt = rsqrtf((float)(deg[t] + 1));
    unsigned v = *reinterpret_cast<const unsigned*>(h + (size_t)t * CDIM + lane * 2);
    float rx = dt * (ax + dt * bf2f((unsigned short)(v & 0xffffu)));
    float ry = dt * (ay + dt * bf2f((unsigned short)(v >> 16)));
    int cnt = min(ocnt[slot], CAPO);
    for (int q = 0; q < cnt; ++q) {
        int i = olist[slot * CAPO + q];
        float2 o; o.x = rx; o.y = ry;
        *reinterpret_cast<float2*>(out + (size_t)i * CDIM + lane * 2) = o;  // coalesced
    }
}

extern "C" void kernel_launch(void* const* d_in, const int* in_sizes, int n_in,
                              void* d_out, int out_size, void* d_ws, size_t ws_size,
                              hipStream_t stream) {
    const int*   nodes = (const int*)d_in[0];
    const int*   eidx  = (const int*)d_in[1];
    const float* emb   = (const float*)d_in[2];
    const float* W     = (const float*)d_in[3];
    float*       out   = (float*)d_out;

    int n = in_sizes[0];             // 10000
    int E = in_sizes[1] / 2;         // 1,600,000
    int N = in_sizes[2] / KDIM;      // 100,000
    const int* erow = eidx;          // sources
    const int* ecol = eidx + E;      // targets

    // workspace carve (~30 MB total)
    char* ws = (char*)d_ws;
    size_t o = 0;
    auto carve = [&](size_t bytes) {
        char* p = ws + o;
        o = (o + bytes + 255) & ~(size_t)255;
        return p;
    };
    int* deg    = (int*)carve((size_t)N * 4);
    int* tmap   = (int*)carve((size_t)N * 4);
    int* tlist  = (int*)carve((size_t)n * 4);
    int* cur    = (int*)carve((size_t)n * 4);
    int* ocnt   = (int*)carve((size_t)n * 4);
    int* olist  = (int*)carve((size_t)n * CAPO * 4);
    int* ucount = (int*)carve(4);
    int* ebuf   = (int*)carve((size_t)n * CAPB * 4);
    unsigned short* wt = (unsigned short*)carve((size_t)16 * 8 * 64 * 8 * 2);   // 128 KB
    unsigned short* h  = (unsigned short*)carve((size_t)N * CDIM * 2);          // 25.6 MB
    (void)ws_size; (void)n_in; (void)out_size;

    hipFuncSetAttribute(reinterpret_cast<const void*>(k_gemm_h),
                        hipFuncAttributeMaxDynamicSharedMemorySize, 65536);

    int E4 = (E + 3) / 4;
    k_init   <<<(N + 255) / 256, 256, 0, stream>>>(deg, tmap, cur, ocnt, ucount, N, n);
    k_targets<<<(n + 255) / 256, 256, 0, stream>>>(nodes, n, tmap, tlist, ucount);
    k_outmap <<<(n + 255) / 256, 256, 0, stream>>>(nodes, n, tmap, ocnt, olist);
    k_degfill<<<(E4 + 255) / 256, 256, 0, stream>>>(erow, ecol, E, deg, tmap, cur, ebuf);
    k_wprep  <<<256, 256, 0, stream>>>(W, wt);
    k_gemm_h <<<(N + 31) / 32, 256, 65536, stream>>>(emb, wt, h, N);
    k_agg    <<<(n + 3) / 4, 256, 0, stream>>>(h, deg, tlist, cur, ebuf, ucount,
                                               ocnt, olist, out);
}

// Round 11
// 178.881 us; speedup vs baseline: 1.1906x; 1.1906x over previous
//
#include <hip/hip_runtime.h>
#include <hip/hip_bf16.h>

// GCN: out = (segment_sum over edges+selfloops of norm * emb[src]) @ W, gathered at `nodes`.
// Round 11: k_gemm_h = NO-LDS register-pipelined streaming GEMM.
// Insight: A (emb rows) has ZERO cross-wave reuse -> LDS staging (r8-r10) was pure
// overhead; B (wt 128 KB) is L2-hot. Direct A->VGPR with depth-4 static prefetch
// (full unroll, rule #20), 8 B-frags issued up-front per step, no barriers.
// 16 waves/CU x 8 KB in-flight A = 128 KB/CU >> Little's-law need.

constexpr int KDIM = 512;   // embedding dim
constexpr int CDIM = 128;   // output channels
constexpr int CAPB = 64;    // bucket capacity per slot (Poisson(16); P(X>=64)~1e-19)
constexpr int CAPO = 16;    // max duplicate output rows per node

typedef __attribute__((ext_vector_type(8))) short short8;   // 8 bf16 (A/B frag)
typedef __attribute__((ext_vector_type(4))) float f32x4;    // C/D frag

static __device__ __forceinline__ unsigned short f2bf(float f) {
    unsigned u = __float_as_uint(f);
    unsigned r = ((u >> 16) & 1u) + 0x7fffu;     // round-to-nearest-even
    return (unsigned short)((u + r) >> 16);
}
static __device__ __forceinline__ float bf2f(unsigned short b) {
    return __uint_as_float(((unsigned)b) << 16);
}

// ---- fused initialization: deg=0, tmap=-1, cur=0, ocnt=0, ucount=0 ----
__global__ void k_init(int* __restrict__ deg, int* __restrict__ tmap,
                       int* __restrict__ cur, int* __restrict__ ocnt,
                       int* __restrict__ ucount, int N, int n) {
    int i = blockIdx.x * blockDim.x + threadIdx.x;
    if (i < N) { deg[i] = 0; tmap[i] = -1; }
    if (i < n) { cur[i] = 0; ocnt[i] = 0; }
    if (i == 0) *ucount = 0;
}

// ---- unique-target compaction: tmap[node] = slot or -1 ----
__global__ void k_targets(const int* __restrict__ nodes, int n,
                          int* __restrict__ tmap, int* __restrict__ tlist,
                          int* __restrict__ ucount) {
    int i = blockIdx.x * blockDim.x + threadIdx.x;
    if (i >= n) return;
    int v = nodes[i];
    if (atomicCAS(&tmap[v], -1, -2) == -1) {   // claim
        int slot = atomicAdd(ucount, 1);
        tlist[slot] = v;
        tmap[v] = slot;                        // only the claimer writes
    }
}

// ---- slot -> list of output rows (handles duplicate nodes) ----
__global__ void k_outmap(const int* __restrict__ nodes, int n,
                         const int* __restrict__ tmap,
                         int* __restrict__ ocnt, int* __restrict__ olist) {
    int i = blockIdx.x * blockDim.x + threadIdx.x;
    if (i >= n) return;
    int slot = tmap[nodes[i]];                 // always >= 0 after k_targets
    int p = atomicAdd(&ocnt[slot], 1);
    if (p < CAPO) olist[slot * CAPO + p] = i;
}

// ---- single edge pass: deg atomics + capacity-bucket fill ----
__global__ __launch_bounds__(256)
void k_degfill(const int* __restrict__ erow, const int* __restrict__ ecol, int E,
               int* __restrict__ deg, const int* __restrict__ tmap,
               int* __restrict__ cur, int* __restrict__ ebuf) {
    int t = blockIdx.x * blockDim.x + threadIdx.x;
    int base = t * 4;
    if (base >= E) return;
    if (base + 4 <= E) {
        int4 c = *reinterpret_cast<const int4*>(ecol + base);
        atomicAdd(&deg[c.x], 1);
        atomicAdd(&deg[c.y], 1);
        atomicAdd(&deg[c.z], 1);
        atomicAdd(&deg[c.w], 1);
        int s0 = tmap[c.x], s1 = tmap[c.y], s2 = tmap[c.z], s3 = tmap[c.w];
        if ((s0 >= 0) | (s1 >= 0) | (s2 >= 0) | (s3 >= 0)) {
            int4 r = *reinterpret_cast<const int4*>(erow + base);
            if (s0 >= 0) { int p = atomicAdd(&cur[s0], 1); if (p < CAPB) ebuf[s0 * CAPB + p] = r.x; }
            if (s1 >= 0) { int p = atomicAdd(&cur[s1], 1); if (p < CAPB) ebuf[s1 * CAPB + p] = r.y; }
            if (s2 >= 0) { int p = atomicAdd(&cur[s2], 1); if (p < CAPB) ebuf[s2 * CAPB + p] = r.z; }
            if (s3 >= 0) { int p = atomicAdd(&cur[s3], 1); if (p < CAPB) ebuf[s3 * CAPB + p] = r.w; }
        }
    } else {
        for (int i = base; i < E; ++i) {
            int c = ecol[i];
            atomicAdd(&deg[c], 1);
            int s = tmap[c];
            if (s >= 0) { int p = atomicAdd(&cur[s], 1); if (p < CAPB) ebuf[s * CAPB + p] = erow[i]; }
        }
    }
}

// ---- pack W (512x128 f32) into bf16 MFMA B-fragment layout ----
// frag (s,t): lane l holds B[k][c], k = s*32 + (l>>4)*8 + j, c = t*16 + (l&15).
// Linear: wt[((s*8+t)*64 + l)*8 + j].
__global__ void k_wprep(const float* __restrict__ W, unsigned short* __restrict__ wt) {
    int idx = blockIdx.x * 256 + threadIdx.x;   // 0..65535
    int j  = idx & 7;
    int l  = (idx >> 3) & 63;
    int st = idx >> 9;
    int t  = st & 7, s = st >> 3;
    int k  = s * 32 + (l >> 4) * 8 + j;
    int c  = t * 16 + (l & 15);
    wt[idx] = f2bf(W[(size_t)k * CDIM + c]);
}

// ---- dense h = emb @ W: no-LDS register-pipelined MFMA GEMM ----
// 256 thr / 4 waves; wave = 16 rows x 128 cols; block = 64 rows; grid 1563.
// A direct global->VGPR, depth-4 prefetch (apf, static idx); B frags from L2.
// A addressing: lane&15 = row, lane>>4 = kq; per row 4 lanes read 128B contiguous/step.
__global__ __launch_bounds__(256, 4)
void k_gemm_h(const float* __restrict__ emb, const unsigned short* __restrict__ wt,
              unsigned short* __restrict__ h, int N) {
    int tid  = threadIdx.x;
    int wave = tid >> 6, lane = tid & 63;
    int row  = blockIdx.x * 64 + wave * 16 + (lane & 15);
    if (row >= N) row = N - 1;              // clamp loads; stores guarded below
    int kq = lane >> 4;                     // k-quarter 0..3
    const float* abase = emb + (size_t)row * KDIM + kq * 8;

    f32x4 acc[8];
    #pragma unroll
    for (int t = 0; t < 8; ++t) acc[t] = (f32x4){0.f, 0.f, 0.f, 0.f};

    float4 apf[4][2];                       // depth-4 A prefetch (static indices only)
    #pragma unroll
    for (int s = 0; s < 4; ++s) {
        apf[s][0] = *reinterpret_cast<const float4*>(abase + s * 32);
        apf[s][1] = *reinterpret_cast<const float4*>(abase + s * 32 + 4);
    }

    const short8* wb = reinterpret_cast<const short8*>(wt);
    #pragma unroll
    for (int ks = 0; ks < 16; ++ks) {
        float4 v0 = apf[ks & 3][0];
        float4 v1 = apf[ks & 3][1];
        if (ks + 4 < 16) {                  // refill slot 4 steps ahead
            apf[ks & 3][0] = *reinterpret_cast<const float4*>(abase + (ks + 4) * 32);
            apf[ks & 3][1] = *reinterpret_cast<const float4*>(abase + (ks + 4) * 32 + 4);
        }
        short8 bf[8];
        const short8* wp = wb + (size_t)(ks * 8) * 64 + lane;
        #pragma unroll
        for (int t = 0; t < 8; ++t) bf[t] = wp[t * 64];   // 8 independent L2 loads
        short8 af;
        af[0] = (short)f2bf(v0.x); af[1] = (short)f2bf(v0.y);
        af[2] = (short)f2bf(v0.z); af[3] = (short)f2bf(v0.w);
        af[4] = (short)f2bf(v1.x); af[5] = (short)f2bf(v1.y);
        af[6] = (short)f2bf(v1.z); af[7] = (short)f2bf(v1.w);
        #pragma unroll
        for (int t = 0; t < 8; ++t)
            acc[t] = __builtin_amdgcn_mfma_f32_16x16x32_bf16(af, bf[t], acc[t], 0, 0, 0);
    }

    // D layout (m89-verified): col = lane&15, row = (lane>>4)*4 + reg_idx
    int rbase = blockIdx.x * 64 + wave * 16 + (lane >> 4) * 4;
    int col   = lane & 15;
    #pragma unroll
    for (int t = 0; t < 8; ++t)
        #pragma unroll
        for (int j = 0; j < 4; ++j) {
            int r = rbase + j;
            if (r < N) h[(size_t)r * CDIM + t * 16 + col] = f2bf(acc[t][j]);
        }
}

// ---- per-target aggregation over h (128-dim bf16): one wave per slot ----
__global__ __launch_bounds__(256)
void k_agg(const unsigned short* __restrict__ h, const int* __restrict__ deg,
           const int* __restrict__ tlist, const int* __restrict__ cur,
           const int* __restrict__ ebuf, const int* __restrict__ ucount,
           const int* __restrict__ ocnt, const int* __restrict__ olist,
           float* __restrict__ out) {
    int u = *ucount;
    int slot = blockIdx.x * 4 + (threadIdx.x >> 6);
    if (slot >= u) return;                 // wave-uniform exit
    int lane = threadIdx.x & 63;
    int e = min(cur[slot], CAPB);
    int myi = 0; float myw = 0.f;
    if (lane < e) {
        myi = ebuf[(size_t)slot * CAPB + lane];          // coalesced
        myw = rsqrtf((float)(deg[myi] + 1));
    }
    float ax = 0.f, ay = 0.f;
    #pragma unroll 4
    for (int j = 0; j < e; ++j) {
        int   src = __shfl(myi, j, 64);
        float w   = __shfl(myw, j, 64);
        unsigned v = *reinterpret_cast<const unsigned*>(h + (size_t)src * CDIM + lane * 2);
        ax += w * bf2f((unsigned short)(v & 0xffffu));
        ay += w * bf2f((unsigned short)(v >> 16));
    }
    int t = tlist[slot];
    float dt = rsqrtf((float)(deg[t] + 1));
    unsigned v = *reinterpret_cast<const unsigned*>(h + (size_t)t * CDIM + lane * 2);
    float rx = dt * (ax + dt * bf2f((unsigned short)(v & 0xffffu)));
    float ry = dt * (ay + dt * bf2f((unsigned short)(v >> 16)));
    int cnt = min(ocnt[slot], CAPO);
    for (int q = 0; q < cnt; ++q) {
        int i = olist[slot * CAPO + q];
        float2 o; o.x = rx; o.y = ry;
        *reinterpret_cast<float2*>(out + (size_t)i * CDIM + lane * 2) = o;  // coalesced
    }
}

extern "C" void kernel_launch(void* const* d_in, const int* in_sizes, int n_in,
                              void* d_out, int out_size, void* d_ws, size_t ws_size,
                              hipStream_t stream) {
    const int*   nodes = (const int*)d_in[0];
    const int*   eidx  = (const int*)d_in[1];
    const float* emb   = (const float*)d_in[2];
    const float* W     = (const float*)d_in[3];
    float*       out   = (float*)d_out;

    int n = in_sizes[0];             // 10000
    int E = in_sizes[1] / 2;         // 1,600,000
    int N = in_sizes[2] / KDIM;      // 100,000
    const int* erow = eidx;          // sources
    const int* ecol = eidx + E;      // targets

    // workspace carve (~30 MB total)
    char* ws = (char*)d_ws;
    size_t o = 0;
    auto carve = [&](size_t bytes) {
        char* p = ws + o;
        o = (o + bytes + 255) & ~(size_t)255;
        return p;
    };
    int* deg    = (int*)carve((size_t)N * 4);
    int* tmap   = (int*)carve((size_t)N * 4);
    int* tlist  = (int*)carve((size_t)n * 4);
    int* cur    = (int*)carve((size_t)n * 4);
    int* ocnt   = (int*)carve((size_t)n * 4);
    int* olist  = (int*)carve((size_t)n * CAPO * 4);
    int* ucount = (int*)carve(4);
    int* ebuf   = (int*)carve((size_t)n * CAPB * 4);
    unsigned short* wt = (unsigned short*)carve((size_t)16 * 8 * 64 * 8 * 2);   // 128 KB
    unsigned short* h  = (unsigned short*)carve((size_t)N * CDIM * 2);          // 25.6 MB
    (void)ws_size; (void)n_in; (void)out_size;

    int E4 = (E + 3) / 4;
    k_init   <<<(N + 255) / 256, 256, 0, stream>>>(deg, tmap, cur, ocnt, ucount, N, n);
    k_targets<<<(n + 255) / 256, 256, 0, stream>>>(nodes, n, tmap, tlist, ucount);
    k_outmap <<<(n + 255) / 256, 256, 0, stream>>>(nodes, n, tmap, ocnt, olist);
    k_degfill<<<(E4 + 255) / 256, 256, 0, stream>>>(erow, ecol, E, deg, tmap, cur, ebuf);
    k_wprep  <<<256, 256, 0, stream>>>(W, wt);
    k_gemm_h <<<(N + 63) / 64, 256, 0, stream>>>(emb, wt, h, N);
    k_agg    <<<(n + 3) / 4, 256, 0, stream>>>(h, deg, tlist, cur, ebuf, ucount,
                                               ocnt, olist, out);
}

// Round 12
// 148.460 us; speedup vs baseline: 1.4346x; 1.2049x over previous
//
#include <hip/hip_runtime.h>
#include <hip/hip_bf16.h>

// GCN: out = (segment_sum over edges+selfloops of norm * emb[src]) @ W, gathered at `nodes`.
// Round 12: consolidation. GEMM = round-9's counted-vmcnt depth-2 pipeline verbatim
// (measured best: ~85us vs 94/105/116/138 for r8/r11/r7/r10 structures). Fusions:
// k_main = degfill blocks (first, retire fast) + gemm blocks (backfill);
// k_prep = wprep + outmap. 7 launches -> 5; degfill (~15us) hidden under gemm.

constexpr int KDIM = 512;   // embedding dim
constexpr int CDIM = 128;   // output channels
constexpr int CAPB = 64;    // bucket capacity per slot (Poisson(16); P(X>=64)~1e-19)
constexpr int CAPO = 16;    // max duplicate output rows per node

typedef __attribute__((ext_vector_type(8))) short short8;   // 8 bf16 (A/B frag)
typedef __attribute__((ext_vector_type(4))) float f32x4;    // C/D frag

static __device__ __forceinline__ unsigned short f2bf(float f) {
    unsigned u = __float_as_uint(f);
    unsigned r = ((u >> 16) & 1u) + 0x7fffu;     // round-to-nearest-even
    return (unsigned short)((u + r) >> 16);
}
static __device__ __forceinline__ float bf2f(unsigned short b) {
    return __uint_as_float(((unsigned)b) << 16);
}

// ---- fused initialization: deg=0, tmap=-1, cur=0, ocnt=0, ucount=0 ----
__global__ void k_init(int* __restrict__ deg, int* __restrict__ tmap,
                       int* __restrict__ cur, int* __restrict__ ocnt,
                       int* __restrict__ ucount, int N, int n) {
    int i = blockIdx.x * blockDim.x + threadIdx.x;
    if (i < N) { deg[i] = 0; tmap[i] = -1; }
    if (i < n) { cur[i] = 0; ocnt[i] = 0; }
    if (i == 0) *ucount = 0;
}

// ---- unique-target compaction: tmap[node] = slot or -1 ----
__global__ void k_targets(const int* __restrict__ nodes, int n,
                          int* __restrict__ tmap, int* __restrict__ tlist,
                          int* __restrict__ ucount) {
    int i = blockIdx.x * blockDim.x + threadIdx.x;
    if (i >= n) return;
    int v = nodes[i];
    if (atomicCAS(&tmap[v], -1, -2) == -1) {   // claim
        int slot = atomicAdd(ucount, 1);
        tlist[slot] = v;
        tmap[v] = slot;                        // only the claimer writes
    }
}

// ---- fused prep: wprep (blocks 0..255) + outmap (blocks 256..295) ----
// wprep: pack W (512x128 f32) -> bf16 MFMA B-frag layout.
// frag (s,t): lane l holds B[k][c], k = s*32 + (l>>4)*8 + j, c = t*16 + (l&15).
// outmap: slot -> list of output rows (handles duplicate nodes).
__global__ void k_prep(const float* __restrict__ W, unsigned short* __restrict__ wt,
                       const int* __restrict__ nodes, int n,
                       const int* __restrict__ tmap,
                       int* __restrict__ ocnt, int* __restrict__ olist) {
    if (blockIdx.x < 256) {
        int idx = blockIdx.x * 256 + threadIdx.x;   // 0..65535
        int j  = idx & 7;
        int l  = (idx >> 3) & 63;
        int st = idx >> 9;
        int t  = st & 7, s = st >> 3;
        int k  = s * 32 + (l >> 4) * 8 + j;
        int c  = t * 16 + (l & 15);
        wt[idx] = f2bf(W[(size_t)k * CDIM + c]);
    } else {
        int i = (blockIdx.x - 256) * 256 + threadIdx.x;
        if (i >= n) return;
        int slot = tmap[nodes[i]];                 // always >= 0 after k_targets
        int p = atomicAdd(&ocnt[slot], 1);
        if (p < CAPO) olist[slot * CAPO + p] = i;
    }
}

// ---- mega kernel: degfill blocks [0, DB) then gemm blocks [DB, DB+GB) ----
// degfill: single edge pass, deg atomics + capacity-bucket fill (512 thr x 4 edges).
// gemm: h = emb @ W, r9 counted-vmcnt depth-2 pipeline: 512 thr / 8 waves
// (4 row-groups x 2 col-groups), tile 128x128, BK=32, 16 K-steps, 3 LDS buffers
// (A[128][32] f32 XOR-swizzled via pre-swizzled source + B 4096 bf16 frag-packed).
__global__ __launch_bounds__(512, 2)
void k_main(const int* __restrict__ erow, const int* __restrict__ ecol, int E,
            int* __restrict__ deg, const int* __restrict__ tmap,
            int* __restrict__ cur, int* __restrict__ ebuf, int DB,
            const float* __restrict__ emb, const unsigned short* __restrict__ wt,
            unsigned short* __restrict__ h, int N) {
    if ((int)blockIdx.x < DB) {
        // ================= degfill =================
        int t = blockIdx.x * 512 + threadIdx.x;
        int base = t * 4;
        if (base >= E) return;
        if (base + 4 <= E) {
            int4 c = *reinterpret_cast<const int4*>(ecol + base);
            atomicAdd(&deg[c.x], 1);
            atomicAdd(&deg[c.y], 1);
            atomicAdd(&deg[c.z], 1);
            atomicAdd(&deg[c.w], 1);
            int s0 = tmap[c.x], s1 = tmap[c.y], s2 = tmap[c.z], s3 = tmap[c.w];
            if ((s0 >= 0) | (s1 >= 0) | (s2 >= 0) | (s3 >= 0)) {
                int4 r = *reinterpret_cast<const int4*>(erow + base);
                if (s0 >= 0) { int p = atomicAdd(&cur[s0], 1); if (p < CAPB) ebuf[s0 * CAPB + p] = r.x; }
                if (s1 >= 0) { int p = atomicAdd(&cur[s1], 1); if (p < CAPB) ebuf[s1 * CAPB + p] = r.y; }
                if (s2 >= 0) { int p = atomicAdd(&cur[s2], 1); if (p < CAPB) ebuf[s2 * CAPB + p] = r.z; }
                if (s3 >= 0) { int p = atomicAdd(&cur[s3], 1); if (p < CAPB) ebuf[s3 * CAPB + p] = r.w; }
            }
        } else {
            for (int i = base; i < E; ++i) {
                int c = ecol[i];
                atomicAdd(&deg[c], 1);
                int s = tmap[c];
                if (s >= 0) { int p = atomicAdd(&cur[s], 1); if (p < CAPB) ebuf[s * CAPB + p] = erow[i]; }
            }
        }
        return;
    }
    // ================= gemm (r9 verbatim) =================
    extern __shared__ char smem[];
    float*          sA = (float*)smem;                        // 3 x 4096 f32
    unsigned short* sB = (unsigned short*)(smem + 3 * 16384); // 3 x 4096 bf16
    int tid  = threadIdx.x;
    int lane = tid & 63;
    int wid  = tid >> 6;
    int wr   = wid >> 1;            // row-group 0..3 (32 rows)
    int wc   = wid & 1;             // col-group 0..1 (64 cols)
    int row0 = ((int)blockIdx.x - DB) * 128;

    auto stage = [&](int buf, int kc) {
        #pragma unroll
        for (int p = 0; p < 2; ++p) {          // A: 1024 x 16B chunks
            int i = p * 512 + tid;
            int row = i >> 3, chunk = i & 7;
            int swz = chunk ^ (row & 7);       // pre-swizzled source, linear LDS
            int rg = row0 + row; if (rg >= N) rg = N - 1;
            const float* g = emb + (size_t)rg * KDIM + kc * 32 + swz * 4;
            float* l = sA + buf * 4096 + i * 4;
            __builtin_amdgcn_global_load_lds(
                (const __attribute__((address_space(1))) void*)g,
                (__attribute__((address_space(3))) void*)l, 16, 0, 0);
        }
        {                                      // B: 512 x 16B chunks
            const unsigned short* g = wt + (size_t)kc * 4096 + tid * 8;
            unsigned short* l = sB + buf * 4096 + tid * 8;
            __builtin_amdgcn_global_load_lds(
                (const __attribute__((address_space(1))) void*)g,
                (__attribute__((address_space(3))) void*)l, 16, 0, 0);
        }
    };

    f32x4 acc[2][4];
    #pragma unroll
    for (int m = 0; m < 2; ++m)
        #pragma unroll
        for (int t = 0; t < 4; ++t) acc[m][t] = (f32x4){0.f, 0.f, 0.f, 0.f};

    int arow0 = wr * 32 + (lane & 15);
    int kq    = lane >> 4;                     // k-quarter 0..3

    auto compute = [&](int buf) {
        const float*          Ab = sA + buf * 4096;
        const unsigned short* Bb = sB + buf * 4096;
        short8 af[2];
        #pragma unroll
        for (int m = 0; m < 2; ++m) {
            int row = arow0 + m * 16;
            int c0  = kq * 2;
            int s0  = c0 ^ (row & 7);
            int s1  = (c0 + 1) ^ (row & 7);
            float4 v0 = *reinterpret_cast<const float4*>(Ab + row * 32 + s0 * 4);
            float4 v1 = *reinterpret_cast<const float4*>(Ab + row * 32 + s1 * 4);
            af[m][0] = (short)f2bf(v0.x); af[m][1] = (short)f2bf(v0.y);
            af[m][2] = (short)f2bf(v0.z); af[m][3] = (short)f2bf(v0.w);
            af[m][4] = (short)f2bf(v1.x); af[m][5] = (short)f2bf(v1.y);
            af[m][6] = (short)f2bf(v1.z); af[m][7] = (short)f2bf(v1.w);
        }
        #pragma unroll
        for (int tt = 0; tt < 4; ++tt) {
            int t = wc * 4 + tt;
            short8 bf = *reinterpret_cast<const short8*>(Bb + ((size_t)(t * 64 + lane)) * 8);
            acc[0][tt] = __builtin_amdgcn_mfma_f32_16x16x32_bf16(af[0], bf, acc[0][tt], 0, 0, 0);
            acc[1][tt] = __builtin_amdgcn_mfma_f32_16x16x32_bf16(af[1], bf, acc[1][tt], 0, 0, 0);
        }
    };

    stage(0, 0); stage(1, 1); stage(2, 2);     // prologue: 3 tiles in flight (9 loads)

    for (int kc = 0; kc < 14; ++kc) {          // steady state: 2 tiles always in flight
        if (kc > 0) stage((kc + 2) % 3, kc + 2);
        asm volatile("s_waitcnt vmcnt(6)" ::: "memory");   // tile kc ready
        __builtin_amdgcn_s_barrier();
        asm volatile("" ::: "memory");
        compute(kc % 3);
        asm volatile("" ::: "memory");
        __builtin_amdgcn_s_barrier();          // frees buf kc%3
    }
    asm volatile("s_waitcnt vmcnt(3)" ::: "memory");       // kc = 14
    __builtin_amdgcn_s_barrier();
    asm volatile("" ::: "memory");
    compute(2);
    asm volatile("" ::: "memory");
    __builtin_amdgcn_s_barrier();
    asm volatile("s_waitcnt vmcnt(0)" ::: "memory");       // kc = 15
    __builtin_amdgcn_s_barrier();
    asm volatile("" ::: "memory");
    compute(0);

    // D layout (m89-verified): col = lane&15, row = (lane>>4)*4 + reg_idx
    int rbase = row0 + wr * 32 + (lane >> 4) * 4;
    int cbase = wc * 64 + (lane & 15);
    #pragma unroll
    for (int m = 0; m < 2; ++m)
        #pragma unroll
        for (int tt = 0; tt < 4; ++tt)
            #pragma unroll
            for (int j = 0; j < 4; ++j) {
                int r = rbase + m * 16 + j;
                if (r < N) h[(size_t)r * CDIM + cbase + tt * 16] = f2bf(acc[m][tt][j]);
            }
}

// ---- per-target aggregation over h (128-dim bf16): one wave per slot ----
__global__ __launch_bounds__(256)
void k_agg(const unsigned short* __restrict__ h, const int* __restrict__ deg,
           const int* __restrict__ tlist, const int* __restrict__ cur,
           const int* __restrict__ ebuf, const int* __restrict__ ucount,
           const int* __restrict__ ocnt, const int* __restrict__ olist,
           float* __restrict__ out) {
    int u = *ucount;
    int slot = blockIdx.x * 4 + (threadIdx.x >> 6);
    if (slot >= u) return;                 // wave-uniform exit
    int lane = threadIdx.x & 63;
    int e = min(cur[slot], CAPB);
    int myi = 0; float myw = 0.f;
    if (lane < e) {
        myi = ebuf[(size_t)slot * CAPB + lane];          // coalesced
        myw = rsqrtf((float)(deg[myi] + 1));
    }
    float ax = 0.f, ay = 0.f;
    #pragma unroll 4
    for (int j = 0; j < e; ++j) {
        int   src = __shfl(myi, j, 64);
        float w   = __shfl(myw, j, 64);
        unsigned v = *reinterpret_cast<const unsigned*>(h + (size_t)src * CDIM + lane * 2);
        ax += w * bf2f((unsigned short)(v & 0xffffu));
        ay += w * bf2f((unsigned short)(v >> 16));
    }
    int t = tlist[slot];
    float dt = rsqrtf((float)(deg[t] + 1));
    unsigned v = *reinterpret_cast<const unsigned*>(h + (size_t)t * CDIM + lane * 2);
    float rx = dt * (ax + dt * bf2f((unsigned short)(v & 0xffffu)));
    float ry = dt * (ay + dt * bf2f((unsigned short)(v >> 16)));
    int cnt = min(ocnt[slot], CAPO);
    for (int q = 0; q < cnt; ++q) {
        int i = olist[slot * CAPO + q];
        float2 o; o.x = rx; o.y = ry;
        *reinterpret_cast<float2*>(out + (size_t)i * CDIM + lane * 2) = o;  // coalesced
    }
}

extern "C" void kernel_launch(void* const* d_in, const int* in_sizes, int n_in,
                              void* d_out, int out_size, void* d_ws, size_t ws_size,
                              hipStream_t stream) {
    const int*   nodes = (const int*)d_in[0];
    const int*   eidx  = (const int*)d_in[1];
    const float* emb   = (const float*)d_in[2];
    const float* W     = (const float*)d_in[3];
    float*       out   = (float*)d_out;

    int n = in_sizes[0];             // 10000
    int E = in_sizes[1] / 2;         // 1,600,000
    int N = in_sizes[2] / KDIM;      // 100,000
    const int* erow = eidx;          // sources
    const int* ecol = eidx + E;      // targets

    // workspace carve (~30 MB total)
    char* ws = (char*)d_ws;
    size_t o = 0;
    auto carve = [&](size_t bytes) {
        char* p = ws + o;
        o = (o + bytes + 255) & ~(size_t)255;
        return p;
    };
    int* deg    = (int*)carve((size_t)N * 4);
    int* tmap   = (int*)carve((size_t)N * 4);
    int* tlist  = (int*)carve((size_t)n * 4);
    int* cur    = (int*)carve((size_t)n * 4);
    int* ocnt   = (int*)carve((size_t)n * 4);
    int* olist  = (int*)carve((size_t)n * CAPO * 4);
    int* ucount = (int*)carve(4);
    int* ebuf   = (int*)carve((size_t)n * CAPB * 4);
    unsigned short* wt = (unsigned short*)carve((size_t)16 * 8 * 64 * 8 * 2);   // 128 KB
    unsigned short* h  = (unsigned short*)carve((size_t)N * CDIM * 2);          // 25.6 MB
    (void)ws_size; (void)n_in; (void)out_size;

    hipFuncSetAttribute(reinterpret_cast<const void*>(k_main),
                        hipFuncAttributeMaxDynamicSharedMemorySize, 73728);

    int DB = (E + 2047) / 2048;      // degfill blocks (512 thr x 4 edges) = 782
    int GB = (N + 127) / 128;        // gemm blocks = 782
    k_init   <<<(N + 255) / 256, 256, 0, stream>>>(deg, tmap, cur, ocnt, ucount, N, n);
    k_targets<<<(n + 255) / 256, 256, 0, stream>>>(nodes, n, tmap, tlist, ucount);
    k_prep   <<<256 + (n + 255) / 256, 256, 0, stream>>>(W, wt, nodes, n, tmap, ocnt, olist);
    k_main   <<<DB + GB, 512, 73728, stream>>>(erow, ecol, E, deg, tmap, cur, ebuf, DB,
                                               emb, wt, h, N);
    k_agg    <<<(n + 3) / 4, 256, 0, stream>>>(h, deg, tlist, cur, ebuf, ucount,
                                               ocnt, olist, out);
}